// Round 2
// baseline (533.094 us; speedup 1.0000x reference)
//
#include <hip/hip_runtime.h>

#define HH 448
#define WW 512
#define NPIX (HH * WW)

// ---- workspace layout (int offsets) ----
#define WS_SORTED1   0                       // 448*512
#define WS_SEG2START 229376                  // 448*16
#define WS_SEG2CNT   236544                  // 448*16
#define WS_PIXINFO   243712                  // 448*512  packed (raw12+2) | rank<<8
#define WS_CNT3      473088                  // 448*192
#define WS_OFFS3     559104                  // 448*192
#define WS_SORTED3   645120                  // 448*512
#define WS_ITEMS     874496                  // up to 448*192
#define WS_NITEMS    960512
#define WS_NEED_INT  960576

struct Res { int idx; float ent; };

__device__ __forceinline__ float lrelu(float v) { return v > 0.0f ? v : 0.01f * v; }

__device__ __forceinline__ Res argmax_ent16(const float* __restrict__ v) {
    float m = v[0]; int idx = 0;
#pragma unroll
    for (int i = 1; i < 16; i++) { if (v[i] > m) { m = v[i]; idx = i; } }
    float s = 0.0f, dot = 0.0f;
#pragma unroll
    for (int i = 0; i < 16; i++) {
        float t = __expf(v[i] - m);
        s += t;
        dot = fmaf(t, v[i], dot);
    }
    Res r; r.idx = idx; r.ent = m + __logf(s) - dot / s;
    return r;
}

// y[o] = b[o] + sum_i x[i] * w[i*OUT + o]   (layout [in][out]; works for global or LDS ptr)
template <int OUT>
__device__ __forceinline__ void layer_g(const float* __restrict__ wmat,
                                        const float* __restrict__ bias,
                                        const float* __restrict__ x,
                                        float* __restrict__ y) {
    float acc[OUT];
#pragma unroll
    for (int o = 0; o < OUT; o++) acc[o] = bias[o];
#pragma unroll
    for (int i = 0; i < 32; i++) {
        float xi = x[i];
        const float4* row = (const float4*)(wmat + i * OUT);
#pragma unroll
        for (int q = 0; q < OUT / 4; q++) {
            float4 wv = row[q];
            acc[4 * q + 0] = fmaf(xi, wv.x, acc[4 * q + 0]);
            acc[4 * q + 1] = fmaf(xi, wv.y, acc[4 * q + 1]);
            acc[4 * q + 2] = fmaf(xi, wv.z, acc[4 * q + 2]);
            acc[4 * q + 3] = fmaf(xi, wv.w, acc[4 * q + 3]);
        }
    }
#pragma unroll
    for (int o = 0; o < OUT; o++) y[o] = acc[o];
}

// y[o] = b[o] + sum_i x[i] * w[o*32 + i]   (stage-1 layout [out][in], LDS broadcast)
template <int OUT>
__device__ __forceinline__ void layer_lds(const float* __restrict__ sw,
                                          const float* __restrict__ sb,
                                          const float* __restrict__ x,
                                          float* __restrict__ y) {
#pragma unroll
    for (int o = 0; o < OUT; o++) {
        const float4* row = (const float4*)(sw + o * 32);
        float a = sb[o];
#pragma unroll
        for (int q = 0; q < 8; q++) {
            float4 wv = row[q];
            a = fmaf(wv.x, x[4 * q + 0], a);
            a = fmaf(wv.y, x[4 * q + 1], a);
            a = fmaf(wv.z, x[4 * q + 2], a);
            a = fmaf(wv.w, x[4 * q + 3], a);
        }
        y[o] = a;
    }
}

// expert MLP 32->32->32->16 from LDS weights (layout: w0[1024] w1[1024] w2[512] b0@2560 b1@2592 b2@2624)
__device__ __forceinline__ Res expert_mlp(const float* __restrict__ sw, float* __restrict__ x) {
    float y[32];
    layer_g<32>(sw, sw + 2560, x, y);
#pragma unroll
    for (int o = 0; o < 32; o++) y[o] = lrelu(y[o]);
    layer_g<32>(sw + 1024, sw + 2592, y, x);
#pragma unroll
    for (int o = 0; o < 32; o++) x[o] = lrelu(x[o]);
    float z[16];
    layer_g<16>(sw + 2048, sw + 2624, x, z);
    return argmax_ent16(z);
}

// ---------------- kernel A: stage 1 + 16-bin sort ----------------
__global__ __launch_bounds__(512) void k_stage1(
    const float* __restrict__ x_in,
    const float* __restrict__ w1_0, const float* __restrict__ b1_0,
    const float* __restrict__ w1_1, const float* __restrict__ b1_1,
    const float* __restrict__ w1_2, const float* __restrict__ b1_2,
    float* __restrict__ out, int* __restrict__ ws) {
    __shared__ float s1[2640];
    __shared__ int sCls[512];
    __shared__ int sCnt[16], sOffs[16];
    const int h = blockIdx.x;
    const int t = threadIdx.x;

    if (t < 192) ws[WS_CNT3 + h * 192 + t] = 0;
    if (h == 0 && t == 0) ws[WS_NITEMS] = 0;

    {
        const float* g0 = w1_0 + (size_t)h * 1024;
        const float* g1 = w1_1 + (size_t)h * 1024;
        for (int idx = t; idx < 1024; idx += 512) {
            s1[idx] = g0[idx];
            s1[1024 + idx] = g1[idx];
        }
        s1[2048 + t] = w1_2[(size_t)h * 512 + t];
        if (t < 32) {
            s1[2560 + t] = b1_0[(size_t)h * 32 + t];
            s1[2592 + t] = b1_1[(size_t)h * 32 + t];
        }
        if (t < 16) s1[2624 + t] = b1_2[(size_t)h * 16 + t];
        if (t < 16) sCnt[t] = 0;
    }
    __syncthreads();

    float x[32], y[32], z16[16];
#pragma unroll
    for (int c = 0; c < 32; c++) x[c] = x_in[(size_t)c * NPIX + (size_t)h * WW + t];
    layer_lds<32>(s1, s1 + 2560, x, y);
#pragma unroll
    for (int o = 0; o < 32; o++) y[o] = lrelu(y[o]);
    layer_lds<32>(s1 + 1024, s1 + 2592, y, x);
#pragma unroll
    for (int o = 0; o < 32; o++) x[o] = lrelu(x[o]);
    layer_lds<16>(s1 + 2048, s1 + 2624, x, z16);
    Res r = argmax_ent16(z16);
    out[NPIX + (size_t)h * WW + t] = r.ent;  // e1
    sCls[t] = r.idx;
    __syncthreads();

    int rank = atomicAdd(&sCnt[sCls[t]], 1);
    __syncthreads();
    if (t < 16) {
        int v = sCnt[t];
        int incl = v;
#pragma unroll
        for (int d = 1; d < 16; d <<= 1) {
            int n = __shfl_up(incl, d, 64);
            if (t >= d) incl += n;
        }
        sOffs[t] = incl - v;
        ws[WS_SEG2START + h * 16 + t] = incl - v;
        ws[WS_SEG2CNT + h * 16 + t] = v;
    }
    __syncthreads();
    ws[WS_SORTED1 + h * 512 + sOffs[sCls[t]] + rank] = t;
}

// ---------------- kernel B: stage 2, one block per (line, class1) ----------------
__global__ __launch_bounds__(64) void k_stage2(
    const float* __restrict__ x_in,
    const float* __restrict__ w2_0, const float* __restrict__ b2_0,
    const float* __restrict__ w2_1, const float* __restrict__ b2_1,
    const float* __restrict__ w2_2, const float* __restrict__ b2_2,
    float* __restrict__ out, int* __restrict__ ws) {
    const int c = blockIdx.x;
    const int h = blockIdx.y;
    const int t = threadIdx.x;
    const int cnt = ws[WS_SEG2CNT + h * 16 + c];
    if (cnt == 0) return;
    const int start = ws[WS_SEG2START + h * 16 + c];

    __shared__ float sw[2640];
    const size_t e = (size_t)h * 16 + c;
    {
        const float4* g0 = (const float4*)(w2_0 + e * 1024);
        const float4* g1 = (const float4*)(w2_1 + e * 1024);
        const float4* g2 = (const float4*)(w2_2 + e * 512);
        float4* s4 = (float4*)sw;
        for (int i = t; i < 256; i += 64) s4[i] = g0[i];
        for (int i = t; i < 256; i += 64) s4[256 + i] = g1[i];
        for (int i = t; i < 128; i += 64) s4[512 + i] = g2[i];
        if (t < 32) sw[2560 + t] = b2_0[e * 32 + t];
        if (t < 32) sw[2592 + t] = b2_1[e * 32 + t];
        if (t < 16) sw[2624 + t] = b2_2[e * 16 + t];
    }
    __syncthreads();

    const float* xb = x_in + (size_t)32 * NPIX + (size_t)h * WW;
    const int* srt = ws + WS_SORTED1 + h * 512 + start;
    for (int k = t; k < cnt; k += 64) {
        int p = srt[k];
        float x[32];
#pragma unroll
        for (int i = 0; i < 32; i++) x[i] = xb[(size_t)i * NPIX + p];
        Res r = expert_mlp(sw, x);
        out[2 * NPIX + (size_t)h * WW + p] = r.ent;  // e2
        int raw = c * 12 + r.idx - 2;
        int cl = raw < 0 ? 0 : (raw > 191 ? 191 : raw);
        int rank = atomicAdd(ws + WS_CNT3 + h * 192 + cl, 1);
        ws[WS_PIXINFO + h * 512 + p] = (raw + 2) | (rank << 8);
    }
}

// ---------------- kernel C: per-line 192-bin scan + scatter + item list ----------------
__global__ __launch_bounds__(512) void k_scan3(int* __restrict__ ws) {
    const int h = blockIdx.x;
    const int t = threadIdx.x;
    __shared__ int sScan[192];
    __shared__ int sOffs[192];
    int cnt = 0;
    if (t < 192) {
        cnt = ws[WS_CNT3 + h * 192 + t];
        int incl = cnt;
#pragma unroll
        for (int d = 1; d < 64; d <<= 1) {
            int n = __shfl_up(incl, d, 64);
            if ((t & 63) >= d) incl += n;
        }
        sScan[t] = incl;
    }
    __syncthreads();
    if (t < 192) {
        int add = 0;
        if (t >= 64) add += sScan[63];
        if (t >= 128) add += sScan[127];
        int offs = sScan[t] + add - cnt;
        sOffs[t] = offs;
        ws[WS_OFFS3 + h * 192 + t] = offs;
        if (cnt > 0) {
            int pos = atomicAdd(ws + WS_NITEMS, 1);
            ws[WS_ITEMS + pos] = h * 192 + t;
        }
    }
    __syncthreads();
    int info = ws[WS_PIXINFO + h * 512 + t];
    int raw = (info & 255) - 2;
    int cl = raw < 0 ? 0 : (raw > 191 ? 191 : raw);
    ws[WS_SORTED3 + h * 512 + sOffs[cl] + (info >> 8)] = t;
}

// ---------------- kernel D: stage 3, grid-stride over compact item list ----------------
__global__ __launch_bounds__(64) void k_stage3(
    const float* __restrict__ x_in,
    const float* __restrict__ w3_0, const float* __restrict__ b3_0,
    const float* __restrict__ w3_1, const float* __restrict__ b3_1,
    const float* __restrict__ w3_2, const float* __restrict__ b3_2,
    float* __restrict__ out, int* __restrict__ ws) {
    __shared__ float sw[2640];
    const int t = threadIdx.x;
    const int nIt = ws[WS_NITEMS];
    for (int it = blockIdx.x; it < nIt; it += gridDim.x) {
        const int item = ws[WS_ITEMS + it];
        const int h = item / 192;
        const int cnt = ws[WS_CNT3 + item];
        const int start = ws[WS_OFFS3 + item];
        const size_t e = (size_t)item;
        {
            const float4* g0 = (const float4*)(w3_0 + e * 1024);
            const float4* g1 = (const float4*)(w3_1 + e * 1024);
            const float4* g2 = (const float4*)(w3_2 + e * 512);
            float4* s4 = (float4*)sw;
            for (int i = t; i < 256; i += 64) s4[i] = g0[i];
            for (int i = t; i < 256; i += 64) s4[256 + i] = g1[i];
            for (int i = t; i < 128; i += 64) s4[512 + i] = g2[i];
            if (t < 32) sw[2560 + t] = b3_0[e * 32 + t];
            if (t < 32) sw[2592 + t] = b3_1[e * 32 + t];
            if (t < 16) sw[2624 + t] = b3_2[e * 16 + t];
        }
        __syncthreads();
        const float* xb = x_in + (size_t)64 * NPIX + (size_t)h * WW;
        for (int k = t; k < cnt; k += 64) {
            int p = ws[WS_SORTED3 + h * 512 + start + k];
            float x[32];
#pragma unroll
            for (int i = 0; i < 32; i++) x[i] = xb[(size_t)i * NPIX + p];
            Res r = expert_mlp(sw, x);
            out[3 * NPIX + (size_t)h * WW + p] = r.ent;  // e3
            int info = ws[WS_PIXINFO + h * 512 + p];
            int raw = (info & 255) - 2;
            int i123 = raw * 8 + r.idx - 4;
            i123 = i123 < 0 ? 0 : (i123 > 1535 ? 1535 : i123);
            out[(size_t)h * WW + p] = (float)i123;
        }
        __syncthreads();
    }
}

// ---------------- fallback: round-1 monolithic kernel (used if ws too small) ----------------
__device__ __noinline__ Res condmul3(const float* __restrict__ xbase, int p,
                                     const float* __restrict__ w0, const float* __restrict__ b0,
                                     const float* __restrict__ w1, const float* __restrict__ b1,
                                     const float* __restrict__ w2, const float* __restrict__ b2,
                                     long e) {
    float x[32], y[32];
#pragma unroll
    for (int c = 0; c < 32; c++) x[c] = xbase[(size_t)c * NPIX + p];
    layer_g<32>(w0 + (size_t)e * 1024, b0 + (size_t)e * 32, x, y);
#pragma unroll
    for (int o = 0; o < 32; o++) y[o] = lrelu(y[o]);
    layer_g<32>(w1 + (size_t)e * 1024, b1 + (size_t)e * 32, y, x);
#pragma unroll
    for (int o = 0; o < 32; o++) x[o] = lrelu(x[o]);
    float z[16];
    layer_g<16>(w2 + (size_t)e * 512, b2 + (size_t)e * 16, x, z);
    return argmax_ent16(z);
}

__global__ __launch_bounds__(512) void cls3_kernel(
    const float* __restrict__ x_in,
    const float* __restrict__ w1_0, const float* __restrict__ b1_0,
    const float* __restrict__ w1_1, const float* __restrict__ b1_1,
    const float* __restrict__ w1_2, const float* __restrict__ b1_2,
    const float* __restrict__ w2_0, const float* __restrict__ b2_0,
    const float* __restrict__ w2_1, const float* __restrict__ b2_1,
    const float* __restrict__ w2_2, const float* __restrict__ b2_2,
    const float* __restrict__ w3_0, const float* __restrict__ b3_0,
    const float* __restrict__ w3_1, const float* __restrict__ b3_1,
    const float* __restrict__ w3_2, const float* __restrict__ b3_2,
    float* __restrict__ out) {
    __shared__ float s1[2640];
    __shared__ int sCls[512];
    __shared__ int sRaw[512];
    __shared__ int sPerm[512];
    __shared__ int sCnt[192];
    __shared__ int sScan[192];
    __shared__ int sOffs[192];
    const int h = blockIdx.x;
    const int t = threadIdx.x;
    {
        const float* g0 = w1_0 + (size_t)h * 1024;
        const float* g1 = w1_1 + (size_t)h * 1024;
        for (int idx = t; idx < 1024; idx += 512) {
            s1[idx] = g0[idx];
            s1[1024 + idx] = g1[idx];
        }
        s1[2048 + t] = w1_2[(size_t)h * 512 + t];
        if (t < 32) {
            s1[2560 + t] = b1_0[(size_t)h * 32 + t];
            s1[2592 + t] = b1_1[(size_t)h * 32 + t];
        }
        if (t < 16) s1[2624 + t] = b1_2[(size_t)h * 16 + t];
    }
    __syncthreads();
    {
        float x[32], y[32], z16[16];
#pragma unroll
        for (int c = 0; c < 32; c++) x[c] = x_in[(size_t)c * NPIX + (size_t)h * WW + t];
        layer_lds<32>(s1, s1 + 2560, x, y);
#pragma unroll
        for (int o = 0; o < 32; o++) y[o] = lrelu(y[o]);
        layer_lds<32>(s1 + 1024, s1 + 2592, y, x);
#pragma unroll
        for (int o = 0; o < 32; o++) x[o] = lrelu(x[o]);
        layer_lds<16>(s1 + 2048, s1 + 2624, x, z16);
        Res r = argmax_ent16(z16);
        out[NPIX + (size_t)h * WW + t] = r.ent;
        sCls[t] = r.idx;
    }
    __syncthreads();
    if (t < 192) sCnt[t] = 0;
    __syncthreads();
    int rank = atomicAdd(&sCnt[sCls[t]], 1);
    __syncthreads();
    if (t < 192) {
        int v = sCnt[t];
        int incl = v;
#pragma unroll
        for (int d = 1; d < 64; d <<= 1) {
            int n = __shfl_up(incl, d, 64);
            if ((t & 63) >= d) incl += n;
        }
        sScan[t] = incl;
    }
    __syncthreads();
    if (t < 192) {
        int add = 0;
        if (t >= 64) add += sScan[63];
        if (t >= 128) add += sScan[127];
        sOffs[t] = sScan[t] + add - sCnt[t];
    }
    __syncthreads();
    sPerm[sOffs[sCls[t]] + rank] = t;
    __syncthreads();
    {
        int p = sPerm[t];
        int c1 = sCls[p];
        long e = (long)h * 16 + c1;
        Res r = condmul3(x_in + (size_t)32 * NPIX + (size_t)h * WW, p,
                         w2_0, b2_0, w2_1, b2_1, w2_2, b2_2, e);
        out[2 * NPIX + (size_t)h * WW + p] = r.ent;
        int raw = c1 * 12 + r.idx - 2;
        sRaw[p] = raw;
        int cl = raw < 0 ? 0 : (raw > 191 ? 191 : raw);
        sCls[p] = cl;
    }
    __syncthreads();
    if (t < 192) sCnt[t] = 0;
    __syncthreads();
    rank = atomicAdd(&sCnt[sCls[t]], 1);
    __syncthreads();
    if (t < 192) {
        int v = sCnt[t];
        int incl = v;
#pragma unroll
        for (int d = 1; d < 64; d <<= 1) {
            int n = __shfl_up(incl, d, 64);
            if ((t & 63) >= d) incl += n;
        }
        sScan[t] = incl;
    }
    __syncthreads();
    if (t < 192) {
        int add = 0;
        if (t >= 64) add += sScan[63];
        if (t >= 128) add += sScan[127];
        sOffs[t] = sScan[t] + add - sCnt[t];
    }
    __syncthreads();
    sPerm[sOffs[sCls[t]] + rank] = t;
    __syncthreads();
    {
        int p = sPerm[t];
        int cl = sCls[p];
        int raw = sRaw[p];
        long e = (long)h * 192 + cl;
        Res r = condmul3(x_in + (size_t)64 * NPIX + (size_t)h * WW, p,
                         w3_0, b3_0, w3_1, b3_1, w3_2, b3_2, e);
        out[3 * NPIX + (size_t)h * WW + p] = r.ent;
        int i123 = raw * 8 + r.idx - 4;
        i123 = i123 < 0 ? 0 : (i123 > 1535 ? 1535 : i123);
        out[(size_t)h * WW + p] = (float)i123;
    }
}

extern "C" void kernel_launch(void* const* d_in, const int* in_sizes, int n_in,
                              void* d_out, int out_size, void* d_ws, size_t ws_size,
                              hipStream_t stream) {
    const float* P[19];
    for (int i = 0; i < 19 && i < n_in; i++) P[i] = (const float*)d_in[i];

    const float *x_in, *W1[3], *B1[3], *W2[3], *B2[3], *W3[3], *B3[3];
    x_in = P[0];
    bool dict_order = (in_sizes[2] == 448 * 32);
    if (dict_order) {
        W1[0] = P[1];  B1[0] = P[2];  W1[1] = P[3];  B1[1] = P[4];  W1[2] = P[5];  B1[2] = P[6];
        W2[0] = P[7];  B2[0] = P[8];  W2[1] = P[9];  B2[1] = P[10]; W2[2] = P[11]; B2[2] = P[12];
        W3[0] = P[13]; B3[0] = P[14]; W3[1] = P[15]; B3[1] = P[16]; W3[2] = P[17]; B3[2] = P[18];
    } else {
        W1[0] = P[1];  W1[1] = P[2];  W1[2] = P[3];  B1[0] = P[4];  B1[1] = P[5];  B1[2] = P[6];
        W2[0] = P[7];  W2[1] = P[8];  W2[2] = P[9];  B2[0] = P[10]; B2[1] = P[11]; B2[2] = P[12];
        W3[0] = P[13]; W3[1] = P[14]; W3[2] = P[15]; B3[0] = P[16]; B3[1] = P[17]; B3[2] = P[18];
    }

    float* out = (float*)d_out;

    if (ws_size < (size_t)WS_NEED_INT * sizeof(int)) {
        // fallback: monolithic round-1 kernel
        hipLaunchKernelGGL(cls3_kernel, dim3(HH), dim3(WW), 0, stream,
                           x_in,
                           W1[0], B1[0], W1[1], B1[1], W1[2], B1[2],
                           W2[0], B2[0], W2[1], B2[1], W2[2], B2[2],
                           W3[0], B3[0], W3[1], B3[1], W3[2], B3[2],
                           out);
        return;
    }

    int* ws = (int*)d_ws;
    hipLaunchKernelGGL(k_stage1, dim3(HH), dim3(WW), 0, stream,
                       x_in, W1[0], B1[0], W1[1], B1[1], W1[2], B1[2], out, ws);
    hipLaunchKernelGGL(k_stage2, dim3(16, HH), dim3(64), 0, stream,
                       x_in, W2[0], B2[0], W2[1], B2[1], W2[2], B2[2], out, ws);
    hipLaunchKernelGGL(k_scan3, dim3(HH), dim3(WW), 0, stream, ws);
    hipLaunchKernelGGL(k_stage3, dim3(4096), dim3(64), 0, stream,
                       x_in, W3[0], B3[0], W3[1], B3[1], W3[2], B3[2], out, ws);
}

// Round 3
// 504.737 us; speedup vs baseline: 1.0562x; 1.0562x over previous
//
#include <hip/hip_runtime.h>

#define HH 448
#define WW 512
#define NPIX (HH * WW)

struct Res { int idx; float ent; };

__device__ __forceinline__ float lrelu(float v) { return v > 0.0f ? v : 0.01f * v; }

__device__ __forceinline__ Res argmax_ent16(const float* __restrict__ v) {
    float m = v[0]; int idx = 0;
#pragma unroll
    for (int i = 1; i < 16; i++) { if (v[i] > m) { m = v[i]; idx = i; } }
    float s = 0.0f, dot = 0.0f;
#pragma unroll
    for (int i = 0; i < 16; i++) {
        float t = __expf(v[i] - m);
        s += t;
        dot = fmaf(t, v[i], dot);
    }
    Res r; r.idx = idx; r.ent = m + __logf(s) - dot / s;
    return r;
}

// uniform-weight layer, weight layout [32][OUT] ([in][out]) — stages 2/3.
// w,b are wave-uniform addresses -> scalar loads; x,y per-lane VGPR.
template <int OUT>
__device__ __forceinline__ void layer_u_io(const float* __restrict__ w,
                                           const float* __restrict__ b,
                                           const float* __restrict__ x,
                                           float* __restrict__ y) {
    float acc[OUT];
#pragma unroll
    for (int o = 0; o < OUT; o++) acc[o] = b[o];
#pragma unroll
    for (int i = 0; i < 32; i++) {
        float xi = x[i];
#pragma unroll
        for (int o = 0; o < OUT; o++) acc[o] = fmaf(w[i * OUT + o], xi, acc[o]);
    }
#pragma unroll
    for (int o = 0; o < OUT; o++) y[o] = acc[o];
}

// uniform-weight layer, weight layout [OUT][32] ([out][in]) — stage 1.
template <int OUT>
__device__ __forceinline__ void layer_u_oi(const float* __restrict__ w,
                                           const float* __restrict__ b,
                                           const float* __restrict__ x,
                                           float* __restrict__ y) {
#pragma unroll
    for (int o = 0; o < OUT; o++) {
        float a = b[o];
#pragma unroll
        for (int i = 0; i < 32; i++) a = fmaf(w[o * 32 + i], x[i], a);
        y[o] = a;
    }
}

__global__ __launch_bounds__(512) void cls3_uniform_kernel(
    const float* __restrict__ x_in,
    const float* __restrict__ w1_0, const float* __restrict__ b1_0,
    const float* __restrict__ w1_1, const float* __restrict__ b1_1,
    const float* __restrict__ w1_2, const float* __restrict__ b1_2,
    const float* __restrict__ w2_0, const float* __restrict__ b2_0,
    const float* __restrict__ w2_1, const float* __restrict__ b2_1,
    const float* __restrict__ w2_2, const float* __restrict__ b2_2,
    const float* __restrict__ w3_0, const float* __restrict__ b3_0,
    const float* __restrict__ w3_1, const float* __restrict__ b3_1,
    const float* __restrict__ w3_2, const float* __restrict__ b3_2,
    float* __restrict__ out) {
    __shared__ int sCls[512];
    __shared__ int sRaw[512];
    __shared__ int sPerm[512];
    __shared__ int sCnt[192];
    __shared__ int sScan[192];
    __shared__ int sOffs[192];

    const int h = blockIdx.x;
    const int t = threadIdx.x;

    // ---- stage 1: per-line uniform weights (scalar loads), per-pixel MLP ----
    {
        float x[32], a[32], bb[32], z[16];
#pragma unroll
        for (int c = 0; c < 32; c++) x[c] = x_in[(size_t)c * NPIX + (size_t)h * WW + t];
        layer_u_oi<32>(w1_0 + (size_t)h * 1024, b1_0 + (size_t)h * 32, x, a);
#pragma unroll
        for (int o = 0; o < 32; o++) a[o] = lrelu(a[o]);
        layer_u_oi<32>(w1_1 + (size_t)h * 1024, b1_1 + (size_t)h * 32, a, bb);
#pragma unroll
        for (int o = 0; o < 32; o++) bb[o] = lrelu(bb[o]);
        layer_u_oi<16>(w1_2 + (size_t)h * 512, b1_2 + (size_t)h * 16, bb, z);
        Res r = argmax_ent16(z);
        out[NPIX + (size_t)h * WW + t] = r.ent;  // e1
        sCls[t] = r.idx;                         // inds1 in [0,16)
    }
    __syncthreads();

    // ---- counting sort by inds1 (16 bins) ----
    if (t < 192) sCnt[t] = 0;
    __syncthreads();
    int rank = atomicAdd(&sCnt[sCls[t]], 1);
    __syncthreads();
    if (t < 192) {
        int v = sCnt[t];
        int incl = v;
#pragma unroll
        for (int d = 1; d < 64; d <<= 1) {
            int n = __shfl_up(incl, d, 64);
            if ((t & 63) >= d) incl += n;
        }
        sScan[t] = incl;
    }
    __syncthreads();
    if (t < 192) {
        int add = 0;
        if (t >= 64) add += sScan[63];
        if (t >= 128) add += sScan[127];
        sOffs[t] = sScan[t] + add - sCnt[t];
    }
    __syncthreads();
    sPerm[sOffs[sCls[t]] + rank] = t;
    __syncthreads();

    // ---- stage 2: wave-uniform expert loop over sorted pixels ----
    {
        int p = sPerm[t];
        int c1 = sCls[p];
        const float* xb = x_in + (size_t)32 * NPIX + (size_t)h * WW;
        float x[32];
#pragma unroll
        for (int i = 0; i < 32; i++) x[i] = xb[(size_t)i * NPIX + p];
        float zsel[16];
#pragma unroll
        for (int k = 0; k < 16; k++) zsel[k] = 0.0f;
        bool done = false;
        unsigned long long m;
        while ((m = __ballot(!done)) != 0ull) {
            int lead = (int)__builtin_ctzll(m);
            int eu = __builtin_amdgcn_readfirstlane(__shfl(c1, lead, 64));
            size_t e = (size_t)h * 16 + eu;
            float a[32], bb[32], z[16];
            layer_u_io<32>(w2_0 + e * 1024, b2_0 + e * 32, x, a);
#pragma unroll
            for (int o = 0; o < 32; o++) a[o] = lrelu(a[o]);
            layer_u_io<32>(w2_1 + e * 1024, b2_1 + e * 32, a, bb);
#pragma unroll
            for (int o = 0; o < 32; o++) bb[o] = lrelu(bb[o]);
            layer_u_io<16>(w2_2 + e * 512, b2_2 + e * 16, bb, z);
            bool mine = (!done) && (c1 == eu);
#pragma unroll
            for (int k = 0; k < 16; k++) zsel[k] = mine ? z[k] : zsel[k];
            done = done || mine;
        }
        Res r = argmax_ent16(zsel);
        out[2 * NPIX + (size_t)h * WW + p] = r.ent;  // e2
        int raw = c1 * 12 + r.idx - 2;               // inds12 (unclipped)
        sRaw[p] = raw;
        int cl = raw < 0 ? 0 : (raw > 191 ? 191 : raw);
        sCls[p] = cl;  // own slot only -> no race
    }
    __syncthreads();

    // ---- counting sort by clipped inds12 (192 bins) ----
    if (t < 192) sCnt[t] = 0;
    __syncthreads();
    rank = atomicAdd(&sCnt[sCls[t]], 1);
    __syncthreads();
    if (t < 192) {
        int v = sCnt[t];
        int incl = v;
#pragma unroll
        for (int d = 1; d < 64; d <<= 1) {
            int n = __shfl_up(incl, d, 64);
            if ((t & 63) >= d) incl += n;
        }
        sScan[t] = incl;
    }
    __syncthreads();
    if (t < 192) {
        int add = 0;
        if (t >= 64) add += sScan[63];
        if (t >= 128) add += sScan[127];
        sOffs[t] = sScan[t] + add - sCnt[t];
    }
    __syncthreads();
    sPerm[sOffs[sCls[t]] + rank] = t;
    __syncthreads();

    // ---- stage 3: wave-uniform expert loop ----
    {
        int p = sPerm[t];
        int cl = sCls[p];
        int raw = sRaw[p];
        const float* xb = x_in + (size_t)64 * NPIX + (size_t)h * WW;
        float x[32];
#pragma unroll
        for (int i = 0; i < 32; i++) x[i] = xb[(size_t)i * NPIX + p];
        float zsel[16];
#pragma unroll
        for (int k = 0; k < 16; k++) zsel[k] = 0.0f;
        bool done = false;
        unsigned long long m;
        while ((m = __ballot(!done)) != 0ull) {
            int lead = (int)__builtin_ctzll(m);
            int eu = __builtin_amdgcn_readfirstlane(__shfl(cl, lead, 64));
            size_t e = (size_t)h * 192 + eu;
            float a[32], bb[32], z[16];
            layer_u_io<32>(w3_0 + e * 1024, b3_0 + e * 32, x, a);
#pragma unroll
            for (int o = 0; o < 32; o++) a[o] = lrelu(a[o]);
            layer_u_io<32>(w3_1 + e * 1024, b3_1 + e * 32, a, bb);
#pragma unroll
            for (int o = 0; o < 32; o++) bb[o] = lrelu(bb[o]);
            layer_u_io<16>(w3_2 + e * 512, b3_2 + e * 16, bb, z);
            bool mine = (!done) && (cl == eu);
#pragma unroll
            for (int k = 0; k < 16; k++) zsel[k] = mine ? z[k] : zsel[k];
            done = done || mine;
        }
        Res r = argmax_ent16(zsel);
        out[3 * NPIX + (size_t)h * WW + p] = r.ent;  // e3
        int i123 = raw * 8 + r.idx - 4;
        i123 = i123 < 0 ? 0 : (i123 > 1535 ? 1535 : i123);
        out[(size_t)h * WW + p] = (float)i123;       // inds123 as float
    }
}

extern "C" void kernel_launch(void* const* d_in, const int* in_sizes, int n_in,
                              void* d_out, int out_size, void* d_ws, size_t ws_size,
                              hipStream_t stream) {
    const float* P[19];
    for (int i = 0; i < 19 && i < n_in; i++) P[i] = (const float*)d_in[i];

    const float *x_in, *W1[3], *B1[3], *W2[3], *B2[3], *W3[3], *B3[3];
    x_in = P[0];
    bool dict_order = (in_sizes[2] == 448 * 32);
    if (dict_order) {
        W1[0] = P[1];  B1[0] = P[2];  W1[1] = P[3];  B1[1] = P[4];  W1[2] = P[5];  B1[2] = P[6];
        W2[0] = P[7];  B2[0] = P[8];  W2[1] = P[9];  B2[1] = P[10]; W2[2] = P[11]; B2[2] = P[12];
        W3[0] = P[13]; B3[0] = P[14]; W3[1] = P[15]; B3[1] = P[16]; W3[2] = P[17]; B3[2] = P[18];
    } else {
        W1[0] = P[1];  W1[1] = P[2];  W1[2] = P[3];  B1[0] = P[4];  B1[1] = P[5];  B1[2] = P[6];
        W2[0] = P[7];  W2[1] = P[8];  W2[2] = P[9];  B2[0] = P[10]; B2[1] = P[11]; B2[2] = P[12];
        W3[0] = P[13]; W3[1] = P[14]; W3[2] = P[15]; B3[0] = P[16]; B3[1] = P[17]; B3[2] = P[18];
    }

    float* out = (float*)d_out;
    hipLaunchKernelGGL(cls3_uniform_kernel, dim3(HH), dim3(WW), 0, stream,
                       x_in,
                       W1[0], B1[0], W1[1], B1[1], W1[2], B1[2],
                       W2[0], B2[0], W2[1], B2[1], W2[2], B2[2],
                       W3[0], B3[0], W3[1], B3[1], W3[2], B3[2],
                       out);
}

// Round 4
// 286.573 us; speedup vs baseline: 1.8602x; 1.7613x over previous
//
#include <hip/hip_runtime.h>

#define HH 448
#define WW 512
#define NPIX (HH * WW)

// ---- workspace layout (int offsets) ----
#define WS_SORTED1  0         // 448*512: p | (c1<<16)
#define WS_PIXINFO  229376    // 448*512: (raw+2) | (rank<<8)
#define WS_CNT3     458752    // 448*192
#define WS_SORTED3  544768    // 448*512: p | ((raw+2)<<16)
#define WS_NEED_INT 774144

struct Res { int idx; float ent; };

__device__ __forceinline__ float lrelu(float v) { return v > 0.0f ? v : 0.01f * v; }

__device__ __forceinline__ Res argmax_ent16(const float* __restrict__ v) {
    float m = v[0]; int idx = 0;
#pragma unroll
    for (int i = 1; i < 16; i++) { if (v[i] > m) { m = v[i]; idx = i; } }
    float s = 0.0f, dot = 0.0f;
#pragma unroll
    for (int i = 0; i < 16; i++) {
        float t = __expf(v[i] - m);
        s += t;
        dot = fmaf(t, v[i], dot);
    }
    Res r; r.idx = idx; r.ent = m + __logf(s) - dot / s;
    return r;
}

// y[o] = b[o] + sum_i x[i] * w[i*OUT + o]   (per-lane global weights, layout [in][out])
template <int OUT>
__device__ __forceinline__ void layer_g(const float* __restrict__ wmat,
                                        const float* __restrict__ bias,
                                        const float* __restrict__ x,
                                        float* __restrict__ y) {
    float acc[OUT];
#pragma unroll
    for (int o = 0; o < OUT; o++) acc[o] = bias[o];
#pragma unroll
    for (int i = 0; i < 32; i++) {
        float xi = x[i];
        const float4* row = (const float4*)(wmat + i * OUT);
#pragma unroll
        for (int q = 0; q < OUT / 4; q++) {
            float4 wv = row[q];
            acc[4 * q + 0] = fmaf(xi, wv.x, acc[4 * q + 0]);
            acc[4 * q + 1] = fmaf(xi, wv.y, acc[4 * q + 1]);
            acc[4 * q + 2] = fmaf(xi, wv.z, acc[4 * q + 2]);
            acc[4 * q + 3] = fmaf(xi, wv.w, acc[4 * q + 3]);
        }
    }
#pragma unroll
    for (int o = 0; o < OUT; o++) y[o] = acc[o];
}

// stage-1 layer from LDS (layout [out][in], wave-broadcast reads)
template <int OUT>
__device__ __forceinline__ void layer_lds(const float* __restrict__ sw,
                                          const float* __restrict__ sb,
                                          const float* __restrict__ x,
                                          float* __restrict__ y) {
#pragma unroll
    for (int o = 0; o < OUT; o++) {
        const float4* row = (const float4*)(sw + o * 32);
        float a = sb[o];
#pragma unroll
        for (int q = 0; q < 8; q++) {
            float4 wv = row[q];
            a = fmaf(wv.x, x[4 * q + 0], a);
            a = fmaf(wv.y, x[4 * q + 1], a);
            a = fmaf(wv.z, x[4 * q + 2], a);
            a = fmaf(wv.w, x[4 * q + 3], a);
        }
        y[o] = a;
    }
}

// full expert MLP 32->32->32->16 with per-lane global weights
__device__ __forceinline__ Res expert_mlp_g(const float* __restrict__ xb, int p,
                                            const float* __restrict__ w0, const float* __restrict__ b0,
                                            const float* __restrict__ w1, const float* __restrict__ b1,
                                            const float* __restrict__ w2, const float* __restrict__ b2,
                                            size_t e) {
    float x[32], y[32];
#pragma unroll
    for (int c = 0; c < 32; c++) x[c] = xb[(size_t)c * NPIX + p];
    layer_g<32>(w0 + e * 1024, b0 + e * 32, x, y);
#pragma unroll
    for (int o = 0; o < 32; o++) y[o] = lrelu(y[o]);
    layer_g<32>(w1 + e * 1024, b1 + e * 32, y, x);
#pragma unroll
    for (int o = 0; o < 32; o++) x[o] = lrelu(x[o]);
    float z[16];
    layer_g<16>(w2 + e * 512, b2 + e * 16, x, z);
    return argmax_ent16(z);
}

// ---------------- k1: stage 1 + 16-bin sort (per line) ----------------
__global__ __launch_bounds__(512) void k_stage1(
    const float* __restrict__ x_in,
    const float* __restrict__ w1_0, const float* __restrict__ b1_0,
    const float* __restrict__ w1_1, const float* __restrict__ b1_1,
    const float* __restrict__ w1_2, const float* __restrict__ b1_2,
    float* __restrict__ out, int* __restrict__ ws) {
    __shared__ float s1[2640];
    __shared__ int sCls[512];
    __shared__ int sCnt[16], sOffs[16];
    const int h = blockIdx.x;
    const int t = threadIdx.x;

    if (t < 192) ws[WS_CNT3 + h * 192 + t] = 0;

    {
        const float* g0 = w1_0 + (size_t)h * 1024;
        const float* g1 = w1_1 + (size_t)h * 1024;
        for (int idx = t; idx < 1024; idx += 512) {
            s1[idx] = g0[idx];
            s1[1024 + idx] = g1[idx];
        }
        s1[2048 + t] = w1_2[(size_t)h * 512 + t];
        if (t < 32) {
            s1[2560 + t] = b1_0[(size_t)h * 32 + t];
            s1[2592 + t] = b1_1[(size_t)h * 32 + t];
        }
        if (t < 16) s1[2624 + t] = b1_2[(size_t)h * 16 + t];
        if (t < 16) sCnt[t] = 0;
    }
    __syncthreads();

    float x[32], y[32], z16[16];
#pragma unroll
    for (int c = 0; c < 32; c++) x[c] = x_in[(size_t)c * NPIX + (size_t)h * WW + t];
    layer_lds<32>(s1, s1 + 2560, x, y);
#pragma unroll
    for (int o = 0; o < 32; o++) y[o] = lrelu(y[o]);
    layer_lds<32>(s1 + 1024, s1 + 2592, y, x);
#pragma unroll
    for (int o = 0; o < 32; o++) x[o] = lrelu(x[o]);
    layer_lds<16>(s1 + 2048, s1 + 2624, x, z16);
    Res r = argmax_ent16(z16);
    out[NPIX + (size_t)h * WW + t] = r.ent;  // e1
    sCls[t] = r.idx;
    __syncthreads();

    int rank = atomicAdd(&sCnt[sCls[t]], 1);
    __syncthreads();
    if (t < 16) {
        int v = sCnt[t];
        int incl = v;
#pragma unroll
        for (int d = 1; d < 16; d <<= 1) {
            int n = __shfl_up(incl, d, 64);
            if (t >= d) incl += n;
        }
        sOffs[t] = incl - v;
    }
    __syncthreads();
    int c = sCls[t];
    ws[WS_SORTED1 + h * WW + sOffs[c] + rank] = t | (c << 16);
}

// ---------------- k2: stage 2, barrier-free, 256-thr blocks ----------------
__global__ __launch_bounds__(256, 1) void k_stage2(
    const float* __restrict__ x_in,
    const float* __restrict__ w2_0, const float* __restrict__ b2_0,
    const float* __restrict__ w2_1, const float* __restrict__ b2_1,
    const float* __restrict__ w2_2, const float* __restrict__ b2_2,
    float* __restrict__ out, int* __restrict__ ws) {
    const int h = blockIdx.x >> 1;
    const int j = ((blockIdx.x & 1) << 8) + threadIdx.x;
    const int v = ws[WS_SORTED1 + h * WW + j];
    const int p = v & 511;
    const int c1 = v >> 16;
    const size_t e = (size_t)h * 16 + c1;
    Res r = expert_mlp_g(x_in + (size_t)32 * NPIX + (size_t)h * WW, p,
                         w2_0, b2_0, w2_1, b2_1, w2_2, b2_2, e);
    out[2 * NPIX + (size_t)h * WW + p] = r.ent;  // e2
    int raw = c1 * 12 + r.idx - 2;
    int cl = raw < 0 ? 0 : (raw > 191 ? 191 : raw);
    int rank = atomicAdd(ws + WS_CNT3 + h * 192 + cl, 1);
    ws[WS_PIXINFO + h * WW + p] = (raw + 2) | (rank << 8);
}

// ---------------- k3: per-line 192-bin scan + scatter ----------------
__global__ __launch_bounds__(512) void k_scan3(int* __restrict__ ws) {
    const int h = blockIdx.x;
    const int t = threadIdx.x;
    __shared__ int sScan[192];
    __shared__ int sOffs[192];
    int cnt = 0;
    if (t < 192) {
        cnt = ws[WS_CNT3 + h * 192 + t];
        int incl = cnt;
#pragma unroll
        for (int d = 1; d < 64; d <<= 1) {
            int n = __shfl_up(incl, d, 64);
            if ((t & 63) >= d) incl += n;
        }
        sScan[t] = incl;
    }
    __syncthreads();
    if (t < 192) {
        int add = 0;
        if (t >= 64) add += sScan[63];
        if (t >= 128) add += sScan[127];
        sOffs[t] = sScan[t] + add - cnt;
    }
    __syncthreads();
    int info = ws[WS_PIXINFO + h * WW + t];
    int raw = (info & 255) - 2;
    int cl = raw < 0 ? 0 : (raw > 191 ? 191 : raw);
    ws[WS_SORTED3 + h * WW + sOffs[cl] + (info >> 8)] = t | ((raw + 2) << 16);
}

// ---------------- k4: stage 3, barrier-free, 256-thr blocks ----------------
__global__ __launch_bounds__(256, 1) void k_stage3(
    const float* __restrict__ x_in,
    const float* __restrict__ w3_0, const float* __restrict__ b3_0,
    const float* __restrict__ w3_1, const float* __restrict__ b3_1,
    const float* __restrict__ w3_2, const float* __restrict__ b3_2,
    float* __restrict__ out, int* __restrict__ ws) {
    const int h = blockIdx.x >> 1;
    const int j = ((blockIdx.x & 1) << 8) + threadIdx.x;
    const int v = ws[WS_SORTED3 + h * WW + j];
    const int p = v & 511;
    const int raw = ((v >> 16) & 255) - 2;
    const int cl = raw < 0 ? 0 : (raw > 191 ? 191 : raw);
    const size_t e = (size_t)h * 192 + cl;
    Res r = expert_mlp_g(x_in + (size_t)64 * NPIX + (size_t)h * WW, p,
                         w3_0, b3_0, w3_1, b3_1, w3_2, b3_2, e);
    out[3 * NPIX + (size_t)h * WW + p] = r.ent;  // e3
    int i123 = raw * 8 + r.idx - 4;
    i123 = i123 < 0 ? 0 : (i123 > 1535 ? 1535 : i123);
    out[(size_t)h * WW + p] = (float)i123;       // inds123 as float
}

extern "C" void kernel_launch(void* const* d_in, const int* in_sizes, int n_in,
                              void* d_out, int out_size, void* d_ws, size_t ws_size,
                              hipStream_t stream) {
    const float* P[19];
    for (int i = 0; i < 19 && i < n_in; i++) P[i] = (const float*)d_in[i];

    const float *x_in, *W1[3], *B1[3], *W2[3], *B2[3], *W3[3], *B3[3];
    x_in = P[0];
    bool dict_order = (in_sizes[2] == 448 * 32);
    if (dict_order) {
        W1[0] = P[1];  B1[0] = P[2];  W1[1] = P[3];  B1[1] = P[4];  W1[2] = P[5];  B1[2] = P[6];
        W2[0] = P[7];  B2[0] = P[8];  W2[1] = P[9];  B2[1] = P[10]; W2[2] = P[11]; B2[2] = P[12];
        W3[0] = P[13]; B3[0] = P[14]; W3[1] = P[15]; B3[1] = P[16]; W3[2] = P[17]; B3[2] = P[18];
    } else {
        W1[0] = P[1];  W1[1] = P[2];  W1[2] = P[3];  B1[0] = P[4];  B1[1] = P[5];  B1[2] = P[6];
        W2[0] = P[7];  W2[1] = P[8];  W2[2] = P[9];  B2[0] = P[10]; B2[1] = P[11]; B2[2] = P[12];
        W3[0] = P[13]; W3[1] = P[14]; W3[2] = P[15]; B3[0] = P[16]; B3[1] = P[17]; B3[2] = P[18];
    }

    float* out = (float*)d_out;
    int* ws = (int*)d_ws;

    hipLaunchKernelGGL(k_stage1, dim3(HH), dim3(WW), 0, stream,
                       x_in, W1[0], B1[0], W1[1], B1[1], W1[2], B1[2], out, ws);
    hipLaunchKernelGGL(k_stage2, dim3(2 * HH), dim3(256), 0, stream,
                       x_in, W2[0], B2[0], W2[1], B2[1], W2[2], B2[2], out, ws);
    hipLaunchKernelGGL(k_scan3, dim3(HH), dim3(WW), 0, stream, ws);
    hipLaunchKernelGGL(k_stage3, dim3(2 * HH), dim3(256), 0, stream,
                       x_in, W3[0], B3[0], W3[1], B3[1], W3[2], B3[2], out, ws);
}

// Round 5
// 201.494 us; speedup vs baseline: 2.6457x; 1.4222x over previous
//
#include <hip/hip_runtime.h>

#define HH 448
#define WW 512
#define NPIX (HH * WW)

struct Res { int idx; float ent; };

__device__ __forceinline__ float lrelu(float v) { return v > 0.0f ? v : 0.01f * v; }

__device__ __forceinline__ Res argmax_ent16(const float* __restrict__ v) {
    float m = v[0]; int idx = 0;
#pragma unroll
    for (int i = 1; i < 16; i++) { if (v[i] > m) { m = v[i]; idx = i; } }
    float s = 0.0f, dot = 0.0f;
#pragma unroll
    for (int i = 0; i < 16; i++) {
        float t = __expf(v[i] - m);
        s += t;
        dot = fmaf(t, v[i], dot);
    }
    Res r; r.idx = idx; r.ent = m + __logf(s) - dot / s;
    return r;
}

// y[o] = b[o] + sum_i x[i] * w[i*OUT + o]   (per-lane global weights, layout [in][out])
template <int OUT>
__device__ __forceinline__ void layer_g(const float* __restrict__ wmat,
                                        const float* __restrict__ bias,
                                        const float* __restrict__ x,
                                        float* __restrict__ y) {
    float acc[OUT];
#pragma unroll
    for (int o = 0; o < OUT; o++) acc[o] = bias[o];
#pragma unroll
    for (int i = 0; i < 32; i++) {
        float xi = x[i];
        const float4* row = (const float4*)(wmat + i * OUT);
#pragma unroll
        for (int q = 0; q < OUT / 4; q++) {
            float4 wv = row[q];
            acc[4 * q + 0] = fmaf(xi, wv.x, acc[4 * q + 0]);
            acc[4 * q + 1] = fmaf(xi, wv.y, acc[4 * q + 1]);
            acc[4 * q + 2] = fmaf(xi, wv.z, acc[4 * q + 2]);
            acc[4 * q + 3] = fmaf(xi, wv.w, acc[4 * q + 3]);
        }
    }
#pragma unroll
    for (int o = 0; o < OUT; o++) y[o] = acc[o];
}

// layer with weight layout [OUT][32] ([out][in]); uniform addresses -> L1 broadcast
template <int OUT>
__device__ __forceinline__ void layer_oi(const float* __restrict__ w,
                                         const float* __restrict__ b,
                                         const float* __restrict__ x,
                                         float* __restrict__ y) {
#pragma unroll
    for (int o = 0; o < OUT; o++) {
        const float4* row = (const float4*)(w + o * 32);
        float a = b[o];
#pragma unroll
        for (int q = 0; q < 8; q++) {
            float4 wv = row[q];
            a = fmaf(wv.x, x[4 * q + 0], a);
            a = fmaf(wv.y, x[4 * q + 1], a);
            a = fmaf(wv.z, x[4 * q + 2], a);
            a = fmaf(wv.w, x[4 * q + 3], a);
        }
        y[o] = a;
    }
}

// full expert MLP 32->32->32->16 with per-lane global weights ([in][out] layout)
__device__ __forceinline__ Res expert_mlp_g(const float* __restrict__ xb, int p,
                                            const float* __restrict__ w0, const float* __restrict__ b0,
                                            const float* __restrict__ w1, const float* __restrict__ b1,
                                            const float* __restrict__ w2, const float* __restrict__ b2,
                                            size_t e) {
    float x[32], y[32];
#pragma unroll
    for (int c = 0; c < 32; c++) x[c] = xb[(size_t)c * NPIX + p];
    layer_g<32>(w0 + e * 1024, b0 + e * 32, x, y);
#pragma unroll
    for (int o = 0; o < 32; o++) y[o] = lrelu(y[o]);
    layer_g<32>(w1 + e * 1024, b1 + e * 32, y, x);
#pragma unroll
    for (int o = 0; o < 32; o++) x[o] = lrelu(x[o]);
    float z[16];
    layer_g<16>(w2 + e * 512, b2 + e * 16, x, z);
    return argmax_ent16(z);
}

__global__ __launch_bounds__(256, 4) void cls3_kernel(
    const float* __restrict__ x_in,
    const float* __restrict__ w1_0, const float* __restrict__ b1_0,
    const float* __restrict__ w1_1, const float* __restrict__ b1_1,
    const float* __restrict__ w1_2, const float* __restrict__ b1_2,
    const float* __restrict__ w2_0, const float* __restrict__ b2_0,
    const float* __restrict__ w2_1, const float* __restrict__ b2_1,
    const float* __restrict__ w2_2, const float* __restrict__ b2_2,
    const float* __restrict__ w3_0, const float* __restrict__ b3_0,
    const float* __restrict__ w3_1, const float* __restrict__ b3_1,
    const float* __restrict__ w3_2, const float* __restrict__ b3_2,
    float* __restrict__ out) {
    __shared__ int sCls[256];
    __shared__ int sRaw[256];
    __shared__ int sPerm[256];
    __shared__ int sCnt[192];
    __shared__ int sScan[192];
    __shared__ int sOffs[192];

    const int h = blockIdx.x >> 1;
    const int base = (blockIdx.x & 1) << 8;   // 0 or 256 within the line
    const int t = threadIdx.x;
    const size_t rowoff = (size_t)h * WW + base;

    // ---- stage 1: per-line weights, wave-uniform global reads ----
    {
        float x[32], a[32], bb[32], z[16];
#pragma unroll
        for (int c = 0; c < 32; c++) x[c] = x_in[(size_t)c * NPIX + rowoff + t];
        layer_oi<32>(w1_0 + (size_t)h * 1024, b1_0 + (size_t)h * 32, x, a);
#pragma unroll
        for (int o = 0; o < 32; o++) a[o] = lrelu(a[o]);
        layer_oi<32>(w1_1 + (size_t)h * 1024, b1_1 + (size_t)h * 32, a, bb);
#pragma unroll
        for (int o = 0; o < 32; o++) bb[o] = lrelu(bb[o]);
        layer_oi<16>(w1_2 + (size_t)h * 512, b1_2 + (size_t)h * 16, bb, z);
        Res r = argmax_ent16(z);
        out[NPIX + rowoff + t] = r.ent;  // e1
        sCls[t] = r.idx;                 // inds1 in [0,16)
    }
    if (t < 16) sCnt[t] = 0;
    __syncthreads();

    // ---- counting sort by inds1 (16 bins, 256 pixels) ----
    int rank = atomicAdd(&sCnt[sCls[t]], 1);
    __syncthreads();
    if (t < 16) {
        int v = sCnt[t];
        int incl = v;
#pragma unroll
        for (int d = 1; d < 16; d <<= 1) {
            int n = __shfl_up(incl, d, 64);
            if (t >= d) incl += n;
        }
        sOffs[t] = incl - v;
    }
    __syncthreads();
    sPerm[sOffs[sCls[t]] + rank] = t;
    __syncthreads();

    // ---- stage 2: sorted order, per-lane weight loads (L1 broadcast within runs) ----
    {
        int p = sPerm[t];
        int c1 = sCls[p];
        size_t e = (size_t)h * 16 + c1;
        Res r = expert_mlp_g(x_in + (size_t)32 * NPIX + rowoff, p,
                             w2_0, b2_0, w2_1, b2_1, w2_2, b2_2, e);
        out[2 * NPIX + rowoff + p] = r.ent;  // e2
        int raw = c1 * 12 + r.idx - 2;       // inds12 (unclipped)
        sRaw[p] = raw;
        int cl = raw < 0 ? 0 : (raw > 191 ? 191 : raw);
        sCls[p] = cl;  // own slot only (sPerm is a permutation) -> no race
    }
    if (t < 192) sCnt[t] = 0;
    __syncthreads();

    // ---- counting sort by clipped inds12 (192 bins, 256 pixels) ----
    rank = atomicAdd(&sCnt[sCls[t]], 1);
    __syncthreads();
    if (t < 192) {
        int v = sCnt[t];
        int incl = v;
#pragma unroll
        for (int d = 1; d < 64; d <<= 1) {
            int n = __shfl_up(incl, d, 64);
            if ((t & 63) >= d) incl += n;
        }
        sScan[t] = incl;
    }
    __syncthreads();
    if (t < 192) {
        int add = 0;
        if (t >= 64) add += sScan[63];
        if (t >= 128) add += sScan[127];
        sOffs[t] = sScan[t] + add - sCnt[t];
    }
    __syncthreads();
    sPerm[sOffs[sCls[t]] + rank] = t;
    __syncthreads();

    // ---- stage 3 ----
    {
        int p = sPerm[t];
        int cl = sCls[p];
        int raw = sRaw[p];
        size_t e = (size_t)h * 192 + cl;
        Res r = expert_mlp_g(x_in + (size_t)64 * NPIX + rowoff, p,
                             w3_0, b3_0, w3_1, b3_1, w3_2, b3_2, e);
        out[3 * NPIX + rowoff + p] = r.ent;  // e3
        int i123 = raw * 8 + r.idx - 4;
        i123 = i123 < 0 ? 0 : (i123 > 1535 ? 1535 : i123);
        out[rowoff + p] = (float)i123;       // inds123 as float
    }
}

extern "C" void kernel_launch(void* const* d_in, const int* in_sizes, int n_in,
                              void* d_out, int out_size, void* d_ws, size_t ws_size,
                              hipStream_t stream) {
    const float* P[19];
    for (int i = 0; i < 19 && i < n_in; i++) P[i] = (const float*)d_in[i];

    const float *x_in, *W1[3], *B1[3], *W2[3], *B2[3], *W3[3], *B3[3];
    x_in = P[0];
    bool dict_order = (in_sizes[2] == 448 * 32);
    if (dict_order) {
        W1[0] = P[1];  B1[0] = P[2];  W1[1] = P[3];  B1[1] = P[4];  W1[2] = P[5];  B1[2] = P[6];
        W2[0] = P[7];  B2[0] = P[8];  W2[1] = P[9];  B2[1] = P[10]; W2[2] = P[11]; B2[2] = P[12];
        W3[0] = P[13]; B3[0] = P[14]; W3[1] = P[15]; B3[1] = P[16]; W3[2] = P[17]; B3[2] = P[18];
    } else {
        W1[0] = P[1];  W1[1] = P[2];  W1[2] = P[3];  B1[0] = P[4];  B1[1] = P[5];  B1[2] = P[6];
        W2[0] = P[7];  W2[1] = P[8];  W2[2] = P[9];  B2[0] = P[10]; B2[1] = P[11]; B2[2] = P[12];
        W3[0] = P[13]; W3[1] = P[14]; W3[2] = P[15]; B3[0] = P[16]; B3[1] = P[17]; B3[2] = P[18];
    }

    float* out = (float*)d_out;
    hipLaunchKernelGGL(cls3_kernel, dim3(2 * HH), dim3(256), 0, stream,
                       x_in,
                       W1[0], B1[0], W1[1], B1[1], W1[2], B1[2],
                       W2[0], B2[0], W2[1], B2[1], W2[2], B2[2],
                       W3[0], B3[0], W3[1], B3[1], W3[2], B3[2],
                       out);
}